// Round 8
// baseline (181.343 us; speedup 1.0000x reference)
//
#include <hip/hip_runtime.h>
#include <hip/hip_bf16.h>
#include <math.h>

#define N_USERS 8192
#define DIMS    128
#define EDGES   262144
#define KCAND   131072
#define NTOT    (EDGES + KCAND)      // 393216
#define LISTCAP 131072
#define CAPB    1024                 // per-block LDS list capacity (entries)
#define NTILES  1056                 // blocks: 128x256 tiles, ri <= 2*cj+1
#define COS_THR 0.3f
#define EPS_SEL 6e-3f                // > hard error bound ~4e-3 of bf16 cos
#define LOGIT_MARGIN 2e-3f

typedef short bf16x8 __attribute__((ext_vector_type(8)));
typedef float f32x4  __attribute__((ext_vector_type(4)));

// u0 tiled layout: slab (i>>7) of 16384 shorts; within slab:
//   [cq = k>>3 (16)][row = i&127 (128)][k&7 (8)]
// -> a wave-quad's MFMA fragment (16 lanes x 16 B) is one 256 B contiguous
//    segment; both operands read DIRECTLY from global (L2-resident, 2 MB).

// exact f32 dot of two normalized rows — __noinline__ so the borderline
// path is ONE code instance, not 32 unrolled clones (R2-R5's fat-epilogue
// mistake; R5->R6 isolate showed the clones cost ~4.5 us).
__attribute__((noinline)) __device__ float exact_dot(const float* __restrict__ a,
                                                     const float* __restrict__ b) {
  float s = 0.f;
  for (int k = 0; k < DIMS; ++k) s = fmaf(a[k], b[k], s);
  return s;
}

// ---------------------------------------------------------------------------
// 1) prep: blocks 0..255 -> normalize with 8 threads/row (bit-exact reference
//    sum order via shfl_xor tree — R2-verified); blocks 256..1279 -> excl
//    bitmask build (nz loaded as uint2).
// ---------------------------------------------------------------------------
__global__ __launch_bounds__(256) void prep_k(const float* __restrict__ x,
                                              const float* __restrict__ W,
                                              const int* __restrict__ nz,
                                              float* __restrict__ un,
                                              unsigned short* __restrict__ u0,
                                              float4* __restrict__ P,
                                              unsigned* __restrict__ excl) {
  if (blockIdx.x < 256) {
#pragma clang fp contract(off)
    const int tid  = threadIdx.x;
    const int rloc = tid >> 3;          // 0..31 rows per block
    const int j    = tid & 7;           // element class k%8
    const int i    = blockIdx.x * 32 + rloc;
    const float* r = x + (size_t)i * DIMS;

    float vals[16];
    float a = 0.f;
#pragma unroll
    for (int b8 = 0; b8 < 16; ++b8) {
      float t = r[b8 * 8 + j];
      vals[b8] = t;
      a = a + t * t;                    // exact a[j] of the reference chain
    }
    // s = ((a0+a1)+(a2+a3)) + ((a4+a5)+(a6+a7)) — xor tree matches exactly
    a = a + __shfl_xor(a, 1, 64);
    a = a + __shfl_xor(a, 2, 64);
    float s = a + __shfl_xor(a, 4, 64);
    float n = (float)sqrt((double)s);
    n = fmaxf(n, 1e-12f);

    unsigned short* slab = u0 + (size_t)(i >> 7) * 16384 + (i & 127) * 8;
    float p0 = 0.f, p1 = 0.f, p2 = 0.f, p3 = 0.f;
#pragma unroll
    for (int b8 = 0; b8 < 16; ++b8) {
      int k = b8 * 8 + j;
      float t = vals[b8];
      float v = t / n;
      un[(size_t)i * DIMS + k] = v;
      __hip_bfloat16 h = __float2bfloat16(v);
      slab[(size_t)b8 * 1024 + j] = *(unsigned short*)&h;
      p0 = fmaf(t, W[k], p0);
      p1 = fmaf(t, W[128 + k], p1);
      p2 = fmaf(t, W[256 + k], p2);
      p3 = fmaf(t, W[384 + k], p3);
    }
#pragma unroll
    for (int m = 1; m < 8; m <<= 1) {
      p0 += __shfl_xor(p0, m, 64);
      p1 += __shfl_xor(p1, m, 64);
      p2 += __shfl_xor(p2, m, 64);
      p3 += __shfl_xor(p3, m, 64);
    }
    if (j == 0) P[i] = make_float4(p0, p1, p2, p3);
  } else {
    int t = (blockIdx.x - 256) * 256 + threadIdx.x;
    if (t < EDGES) {
      uint2 e = ((const uint2*)nz)[t];
      atomicOr(&excl[(size_t)e.x * 256 + (e.y >> 5)], 1u << (e.y & 31));
    }
  }
}

// ---------------------------------------------------------------------------
// 2) mfma_pass (R8: R7's 128x256 tile core + resolve FUSED back in).
//    R7 diagnosis: total is dispatch-count-bound (~8-12 us/boundary x 8).
//    Fusing resolve (R2-verified epilogue logic) kills one dispatch; the
//    borderline exact-dot is a noinline call so the epilogue stays thin.
//    List contains only ALIVE entries; row_cnt built here via atomics.
// ---------------------------------------------------------------------------
__global__ __launch_bounds__(512) void mfma_pass(const unsigned short* __restrict__ u0,
                                                 const float* __restrict__ un,
                                                 const unsigned* __restrict__ excl,
                                                 uint2* __restrict__ list,
                                                 int* __restrict__ gcount,
                                                 int* __restrict__ row_cnt) {
  __shared__ uint2 svec[CAPB];                               // 8 KB
  __shared__ int lcnt, lbase;

  const int tid  = threadIdx.x;
  const int lane = tid & 63;
  const int wv   = tid >> 6;
  const int quad = lane >> 4;
  const int l15  = lane & 15;

  // decode: blocks enumerate (cj, ri) with ri <= 2*cj+1 over a 64(row,128) x
  // 32(col,256) grid; cum(cj) = cj*(cj+1)
  int b = blockIdx.x, cj = 0;
  while ((cj + 1) * (cj + 2) <= b) ++cj;
  const int ri = b - cj * (cj + 1);
  const int I0 = ri * 128, J0 = cj * 256;
  const int moff = (wv & 3) * 32;         // 4 wave rows x 32
  const int nhalf = wv >> 2;              // 2 wave cols x 128
  const int jbase = J0 + nhalf * 128;

  if (tid == 0) lcnt = 0;
  __syncthreads();   // covers lcnt init only

  const unsigned short* __restrict__ Abase = u0 + (size_t)ri * 16384;
  // each wave's 128 B-cols live entirely in ONE slab:
  const unsigned short* __restrict__ Bbase = u0 + (size_t)(cj * 2 + nhalf) * 16384;

  f32x4 acc[2][8];
#pragma unroll
  for (int mt = 0; mt < 2; ++mt)
#pragma unroll
    for (int nt = 0; nt < 8; ++nt)
#pragma unroll
      for (int g = 0; g < 4; ++g) acc[mt][nt][g] = 0.f;

  // ---- 2-deep register-pipelined K loop (static names, kc order 0..3) ----
  bf16x8 a0_0, a0_1, b0_0, b0_1, b0_2, b0_3, b0_4, b0_5, b0_6, b0_7;
  bf16x8 a1_0, a1_1, b1_0, b1_1, b1_2, b1_3, b1_4, b1_5, b1_6, b1_7;

#define LOADF(AN0, AN1, BN0, BN1, BN2, BN3, BN4, BN5, BN6, BN7, KC)           \
  {                                                                           \
    const int cq = (KC) * 4 + quad;                                           \
    AN0 = *(const bf16x8*)&Abase[(size_t)(cq * 128 + moff + l15) * 8];        \
    AN1 = *(const bf16x8*)&Abase[(size_t)(cq * 128 + moff + 16 + l15) * 8];   \
    BN0 = *(const bf16x8*)&Bbase[(size_t)(cq * 128 + 0 * 16 + l15) * 8];      \
    BN1 = *(const bf16x8*)&Bbase[(size_t)(cq * 128 + 1 * 16 + l15) * 8];      \
    BN2 = *(const bf16x8*)&Bbase[(size_t)(cq * 128 + 2 * 16 + l15) * 8];      \
    BN3 = *(const bf16x8*)&Bbase[(size_t)(cq * 128 + 3 * 16 + l15) * 8];      \
    BN4 = *(const bf16x8*)&Bbase[(size_t)(cq * 128 + 4 * 16 + l15) * 8];      \
    BN5 = *(const bf16x8*)&Bbase[(size_t)(cq * 128 + 5 * 16 + l15) * 8];      \
    BN6 = *(const bf16x8*)&Bbase[(size_t)(cq * 128 + 6 * 16 + l15) * 8];      \
    BN7 = *(const bf16x8*)&Bbase[(size_t)(cq * 128 + 7 * 16 + l15) * 8];      \
  }

#define MFMAF(AN0, AN1, BN0, BN1, BN2, BN3, BN4, BN5, BN6, BN7)               \
  {                                                                           \
    acc[0][0] = __builtin_amdgcn_mfma_f32_16x16x32_bf16(AN0, BN0, acc[0][0], 0, 0, 0); \
    acc[0][1] = __builtin_amdgcn_mfma_f32_16x16x32_bf16(AN0, BN1, acc[0][1], 0, 0, 0); \
    acc[0][2] = __builtin_amdgcn_mfma_f32_16x16x32_bf16(AN0, BN2, acc[0][2], 0, 0, 0); \
    acc[0][3] = __builtin_amdgcn_mfma_f32_16x16x32_bf16(AN0, BN3, acc[0][3], 0, 0, 0); \
    acc[0][4] = __builtin_amdgcn_mfma_f32_16x16x32_bf16(AN0, BN4, acc[0][4], 0, 0, 0); \
    acc[0][5] = __builtin_amdgcn_mfma_f32_16x16x32_bf16(AN0, BN5, acc[0][5], 0, 0, 0); \
    acc[0][6] = __builtin_amdgcn_mfma_f32_16x16x32_bf16(AN0, BN6, acc[0][6], 0, 0, 0); \
    acc[0][7] = __builtin_amdgcn_mfma_f32_16x16x32_bf16(AN0, BN7, acc[0][7], 0, 0, 0); \
    acc[1][0] = __builtin_amdgcn_mfma_f32_16x16x32_bf16(AN1, BN0, acc[1][0], 0, 0, 0); \
    acc[1][1] = __builtin_amdgcn_mfma_f32_16x16x32_bf16(AN1, BN1, acc[1][1], 0, 0, 0); \
    acc[1][2] = __builtin_amdgcn_mfma_f32_16x16x32_bf16(AN1, BN2, acc[1][2], 0, 0, 0); \
    acc[1][3] = __builtin_amdgcn_mfma_f32_16x16x32_bf16(AN1, BN3, acc[1][3], 0, 0, 0); \
    acc[1][4] = __builtin_amdgcn_mfma_f32_16x16x32_bf16(AN1, BN4, acc[1][4], 0, 0, 0); \
    acc[1][5] = __builtin_amdgcn_mfma_f32_16x16x32_bf16(AN1, BN5, acc[1][5], 0, 0, 0); \
    acc[1][6] = __builtin_amdgcn_mfma_f32_16x16x32_bf16(AN1, BN6, acc[1][6], 0, 0, 0); \
    acc[1][7] = __builtin_amdgcn_mfma_f32_16x16x32_bf16(AN1, BN7, acc[1][7], 0, 0, 0); \
  }

  LOADF(a0_0, a0_1, b0_0, b0_1, b0_2, b0_3, b0_4, b0_5, b0_6, b0_7, 0)
  LOADF(a1_0, a1_1, b1_0, b1_1, b1_2, b1_3, b1_4, b1_5, b1_6, b1_7, 1)
  MFMAF(a0_0, a0_1, b0_0, b0_1, b0_2, b0_3, b0_4, b0_5, b0_6, b0_7)
  LOADF(a0_0, a0_1, b0_0, b0_1, b0_2, b0_3, b0_4, b0_5, b0_6, b0_7, 2)
  MFMAF(a1_0, a1_1, b1_0, b1_1, b1_2, b1_3, b1_4, b1_5, b1_6, b1_7)
  LOADF(a1_0, a1_1, b1_0, b1_1, b1_2, b1_3, b1_4, b1_5, b1_6, b1_7, 3)
  MFMAF(a0_0, a0_1, b0_0, b0_1, b0_2, b0_3, b0_4, b0_5, b0_6, b0_7)
  MFMAF(a1_0, a1_1, b1_0, b1_1, b1_2, b1_3, b1_4, b1_5, b1_6, b1_7)
#undef LOADF
#undef MFMAF

  // ---- epilogue with fused resolve (R2-verified logic, noinline dot) ----
#pragma unroll
  for (int mt = 0; mt < 2; ++mt)
#pragma unroll
    for (int nt = 0; nt < 8; ++nt)
#pragma unroll
      for (int g = 0; g < 4; ++g) {
        float v = acc[mt][nt][g];
        if (v > COS_THR - EPS_SEL) {
          int i = I0 + moff + mt * 16 + quad * 4 + g;
          int j = jbase + nt * 16 + l15;
          if (j > i) {
            float vv = v;
            bool pass = true;
            if (v <= COS_THR + EPS_SEL) {   // borderline: decide exactly
              vv = exact_dot(un + (size_t)i * DIMS, un + (size_t)j * DIMS);
              pass = (vv > COS_THR);
            }
            if (pass) {
              unsigned wij = excl[(size_t)i * 256 + (j >> 5)];
              unsigned wji = excl[(size_t)j * 256 + (i >> 5)];
              unsigned uvv = __float_as_uint(vv);
              if (!((wij >> (j & 31)) & 1u)) {
                int idx = atomicAdd(&lcnt, 1);
                if (idx < CAPB) {
                  svec[idx] = make_uint2(((unsigned)i << 13) | j, uvv);
                  atomicAdd(&row_cnt[i], 1);
                }
              }
              if (!((wji >> (i & 31)) & 1u)) {
                int idx = atomicAdd(&lcnt, 1);
                if (idx < CAPB) {
                  svec[idx] = make_uint2(((unsigned)j << 13) | i, uvv);
                  atomicAdd(&row_cnt[j], 1);
                }
              }
            }
          }
        }
      }

  __syncthreads();
  int n = min(lcnt, CAPB);
  if (tid == 0) lbase = atomicAdd(gcount, n);
  __syncthreads();
  int base = lbase;
  for (int t = tid; t < n; t += 512) {
    int o = base + t;
    if (o < LISTCAP) list[o] = svec[t];
  }
}

// ---------------------------------------------------------------------------
// shared finalize math (identical arithmetic to the R1/R2-verified finalize)
// ---------------------------------------------------------------------------
__device__ __forceinline__ void emit_out(int p, int i, int j, float wgt,
                                         const float4* __restrict__ P,
                                         const float* __restrict__ b,
                                         const float* __restrict__ g,
                                         const float* __restrict__ ue,
                                         const float* __restrict__ W,
                                         float* __restrict__ out) {
  float4 Pi = P[i], Pj = P[j];
  float l0 = Pi.x + Pj.y + b[0];
  float l1 = Pi.z + Pj.w + b[1];
  float g0 = g[2 * p], g1 = g[2 * p + 1];
  float s0 = l0 + g0, s1 = l1 + g1;

  if (fabsf(s0 - s1) < LOGIT_MARGIN) {
    const float* ri = ue + (size_t)i * DIMS;
    const float* rj = ue + (size_t)j * DIMS;
    float e0 = 0.f, e1 = 0.f;
    for (int k = 0; k < DIMS; ++k) {
      e0 = fmaf(ri[k], W[k], e0);
      e1 = fmaf(ri[k], W[256 + k], e1);
    }
    for (int k = 0; k < DIMS; ++k) {
      e0 = fmaf(rj[k], W[128 + k], e0);
      e1 = fmaf(rj[k], W[384 + k], e1);
    }
    s0 = (e0 + b[0]) + g0;
    s1 = (e1 + b[1]) + g1;
  }

  float w = (s0 >= s1) ? wgt : 0.0f;
  out[p] = w;
  out[NTOT + p] = w;
  out[2 * NTOT + p] = w;
  out[3 * NTOT + 2 * p + 0] = (float)i;
  out[3 * NTOT + 2 * p + 1] = (float)j;
}

// ---------------------------------------------------------------------------
// 3) tail_k (R8): scan + scatter + sort + finalize + pad in ONE dispatch.
//    256 blocks x 256; block bo owns rows [bo*32, bo*32+32).  The only
//    global dependency (prefix over row_cnt) is RECOMPUTED PER BLOCK from
//    the 32 KB row_cnt array (L2-resident) — no inter-block sync needed,
//    no grid.sync (R1's 55 us/sync trap), no scan/scatter/sort/finalize
//    dispatch boundaries (~8-12 us each, the R7 diagnosis).
// ---------------------------------------------------------------------------
__global__ __launch_bounds__(256) void tail_k(const uint2* __restrict__ list,
                                              const int* __restrict__ gcount,
                                              const int* __restrict__ row_cnt,
                                              int* __restrict__ cand_i,
                                              int* __restrict__ cand_j,
                                              float* __restrict__ cand_v,
                                              const float* __restrict__ ue,
                                              const float* __restrict__ W,
                                              const float* __restrict__ b,
                                              const float* __restrict__ g,
                                              const int* __restrict__ nz,
                                              const float4* __restrict__ P,
                                              float* __restrict__ out) {
  __shared__ int s_chunk[256];
  __shared__ int s_off[32];     // owned rows' global candidate offsets
  __shared__ int s_pos[32];     // per-owned-row fill counters
  __shared__ int s_lo, s_M;

  const int tid = threadIdx.x;
  const int bo  = blockIdx.x;   // 0..255

  // ---- per-block full prefix over row_cnt (chunk = 32 rows = one block) ----
  int s = 0;
  {
    const int rb = tid * 32;
    for (int k = 0; k < 32; ++k) s += row_cnt[rb + k];
  }
  s_chunk[tid] = s;
  __syncthreads();
  int x = s;
  for (int d = 1; d < 256; d <<= 1) {
    int y = (tid >= d) ? s_chunk[tid - d] : 0;
    __syncthreads();
    x += y;
    s_chunk[tid] = x;
    __syncthreads();
  }
  if (tid == 255) s_M = x;          // total alive candidates M
  if (tid == bo)  s_lo = x - s;     // exclusive offset of this block's chunk
  __syncthreads();
  if (tid == 0) {
    int run = s_lo;
    for (int k = 0; k < 32; ++k) {
      s_off[k] = run;
      run += row_cnt[bo * 32 + k];
    }
  }
  if (tid < 32) s_pos[tid] = 0;
  __syncthreads();

  const int n = min(*gcount, LISTCAP);
  const int M = s_M;

  // ---- scatter: scan full list, keep entries for owned rows ----
  for (int t = tid; t < n; t += 256) {
    uint2 e = list[t];
    int i = e.x >> 13;
    if ((i >> 5) == bo) {
      int lr = i & 31;
      int pos = s_off[lr] + atomicAdd(&s_pos[lr], 1);
      if (pos < KCAND) {
        cand_i[pos] = i;
        cand_j[pos] = e.x & 8191;
        cand_v[pos] = __uint_as_float(e.y);
      }
    }
  }
  __syncthreads();

  // ---- sort owned rows ascending by j (j unique per row -> deterministic) --
  if (tid < 32) {
    int o = s_off[tid], c = s_pos[tid];
    if (o + c > KCAND) c = max(0, KCAND - o);
    for (int a = 1; a < c; ++a) {
      int jv = cand_j[o + a];
      float vv = cand_v[o + a];
      int bq = a - 1;
      while (bq >= 0 && cand_j[o + bq] > jv) {
        cand_j[o + bq + 1] = cand_j[o + bq];
        cand_v[o + bq + 1] = cand_v[o + bq];
        --bq;
      }
      cand_j[o + bq + 1] = jv;
      cand_v[o + bq + 1] = vv;
    }
  }
  __syncthreads();

  // ---- finalize this block's candidate span [lo, hi) ----
  {
    int lo = s_off[0];
    int hi = min(s_off[31] + s_pos[31], KCAND);
    for (int q = lo + tid; q < hi; q += 256) {
      int ci = cand_i[q], cjj = cand_j[q];
      float wgt = fmaxf(cand_v[q], 0.0f);
      emit_out(EDGES + q, ci, cjj, wgt, P, b, g, ue, W, out);
    }
  }

  // ---- finalize this block's EDGES share: [bo*1024, bo*1024+1024) ----
  for (int p = bo * 1024 + tid; p < bo * 1024 + 1024; p += 256) {
    uint2 e = ((const uint2*)nz)[p];
    emit_out(p, (int)e.x, (int)e.y, 1.0f, P, b, g, ue, W, out);
  }

  // ---- pads: q in [M, KCAND) striped across all blocks ----
  for (int q = M + bo * 256 + tid; q < KCAND; q += 256 * 256) {
    int p = EDGES + q;
    out[p] = 0.0f;
    out[NTOT + p] = 0.0f;
    out[2 * NTOT + p] = 0.0f;
    out[3 * NTOT + 2 * p + 0] = 0.0f;
    out[3 * NTOT + 2 * p + 1] = 0.0f;
  }
}

// ---------------------------------------------------------------------------
extern "C" void kernel_launch(void* const* d_in, const int* in_sizes, int n_in,
                              void* d_out, int out_size, void* d_ws, size_t ws_size,
                              hipStream_t stream) {
  (void)in_sizes; (void)n_in; (void)out_size; (void)ws_size;

  const float* user_emb = (const float*)d_in[0];
  const float* W        = (const float*)d_in[1];
  const float* b        = (const float*)d_in[2];
  const float* gnoise   = (const float*)d_in[3];
  const int*   nz       = (const int*)d_in[4];
  float* out = (float*)d_out;

  char* ws = (char*)d_ws;
  float*          un      = (float*)(ws + 0);                        // 4 MB
  unsigned short* u0      = (unsigned short*)(ws + (4u << 20));      // 2 MB (tiled)
  unsigned*       excl    = (unsigned*)(ws + (6u << 20));            // 8 MB
  // zeroed region directly after excl: gcount | row_cnt
  char*           zbase   = ws + (14u << 20);
  int*            gcount  = (int*)(zbase);                           // 64 B slot
  int*            row_cnt = (int*)(zbase + 64);                      // 32 KB
  uint2*          list    = (uint2*)(ws + (15u << 20));              // 1 MB
  int*            cand_i  = (int*)(ws + (16u << 20));                // 512 KB
  int*            cand_j  = (int*)(ws + (16u << 20) + (512u << 10)); // 512 KB
  float*          cand_v  = (float*)(ws + (17u << 20));              // 512 KB
  float4*         P       = (float4*)(ws + (17u << 20) + (512u << 10)); // 128 KB

  // one memset: excl (8 MB) + counter region (96 KB) are contiguous
  hipMemsetAsync(excl, 0, (8u << 20) + (96u << 10), stream);

  prep_k<<<256 + EDGES / 256, 256, 0, stream>>>(user_emb, W, nz, un, u0, P, excl);
  mfma_pass<<<NTILES, 512, 0, stream>>>(u0, un, excl, list, gcount, row_cnt);
  tail_k<<<256, 256, 0, stream>>>(list, gcount, row_cnt, cand_i, cand_j, cand_v,
                                  user_emb, W, b, gnoise, nz, P, out);
}

// Round 10
// 137.169 us; speedup vs baseline: 1.3220x; 1.3220x over previous
//
#include <hip/hip_runtime.h>
#include <hip/hip_bf16.h>
#include <math.h>

#define N_USERS 8192
#define DIMS    128
#define EDGES   262144
#define KCAND   131072
#define NTOT    (EDGES + KCAND)      // 393216
#define LISTCAP 131072
#define CAPB    2048                 // per-block LDS list capacity (entries)
#define NTILES  528                  // triangular 32x32 grid of 256x256 tiles
#define COS_THR 0.3f
#define EPS_SEL 6e-3f                // > hard error bound ~4e-3 of bf16 cos
#define LOGIT_MARGIN 2e-3f
#define DEADKEY 0xFFFFFFFFu

typedef short bf16x8 __attribute__((ext_vector_type(8)));
typedef float f32x4  __attribute__((ext_vector_type(4)));

// u0 tiled layout: slab (i>>7) of 16384 shorts; within slab:
//   [cq = k>>3 (16)][row = i&127 (128)][k&7 (8)]
// -> a 256-row tile = two consecutive slabs = 64 KB contiguous, and the
//    LDS image below is byte-identical to that slab pair.

// ---------------------------------------------------------------------------
// 1) prep: blocks 0..255 -> normalize with 8 threads/row (bit-exact reference
//    sum order via shfl_xor tree — R2-verified); blocks 256..1279 -> excl
//    bitmask build (nz loaded as uint2).
// ---------------------------------------------------------------------------
__global__ __launch_bounds__(256) void prep_k(const float* __restrict__ x,
                                              const float* __restrict__ W,
                                              const int* __restrict__ nz,
                                              float* __restrict__ un,
                                              unsigned short* __restrict__ u0,
                                              float4* __restrict__ P,
                                              unsigned* __restrict__ excl) {
  if (blockIdx.x < 256) {
#pragma clang fp contract(off)
    const int tid  = threadIdx.x;
    const int rloc = tid >> 3;          // 0..31 rows per block
    const int j    = tid & 7;           // element class k%8
    const int i    = blockIdx.x * 32 + rloc;
    const float* r = x + (size_t)i * DIMS;

    float vals[16];
    float a = 0.f;
#pragma unroll
    for (int b8 = 0; b8 < 16; ++b8) {
      float t = r[b8 * 8 + j];
      vals[b8] = t;
      a = a + t * t;                    // exact a[j] of the reference chain
    }
    // s = ((a0+a1)+(a2+a3)) + ((a4+a5)+(a6+a7)) — xor tree matches exactly
    a = a + __shfl_xor(a, 1, 64);
    a = a + __shfl_xor(a, 2, 64);
    float s = a + __shfl_xor(a, 4, 64);
    float n = (float)sqrt((double)s);
    n = fmaxf(n, 1e-12f);

    unsigned short* slab = u0 + (size_t)(i >> 7) * 16384 + (i & 127) * 8;
    float p0 = 0.f, p1 = 0.f, p2 = 0.f, p3 = 0.f;
#pragma unroll
    for (int b8 = 0; b8 < 16; ++b8) {
      int k = b8 * 8 + j;
      float t = vals[b8];
      float v = t / n;
      un[(size_t)i * DIMS + k] = v;
      __hip_bfloat16 h = __float2bfloat16(v);
      slab[(size_t)b8 * 1024 + j] = *(unsigned short*)&h;
      p0 = fmaf(t, W[k], p0);
      p1 = fmaf(t, W[128 + k], p1);
      p2 = fmaf(t, W[256 + k], p2);
      p3 = fmaf(t, W[384 + k], p3);
    }
#pragma unroll
    for (int m = 1; m < 8; m <<= 1) {
      p0 += __shfl_xor(p0, m, 64);
      p1 += __shfl_xor(p1, m, 64);
      p2 += __shfl_xor(p2, m, 64);
      p3 += __shfl_xor(p3, m, 64);
    }
    if (j == 0) P[i] = make_float4(p0, p1, p2, p3);
  } else {
    int t = (blockIdx.x - 256) * 256 + threadIdx.x;
    if (t < EDGES) {
      uint2 e = ((const uint2*)nz)[t];
      atomicOr(&excl[(size_t)e.x * 256 + (e.y >> 5)], 1u << (e.y & 31));
    }
  }
}

// ---------------------------------------------------------------------------
// 2) mfma_pass (R10 = R9 with the staging overrun FIXED).
//    R9's bug: staging loops ran it=0..7 (128 KB/array) into 64 KB arrays —
//    LDS OOB write + u0 OOB read => GPU fault => container death.  Correct
//    sizing: 4096 uint4 per array / 1024 threads = 4 iterations exactly.
//    Theory unchanged: stageless fragments caused 338 MB of L2 reads
//    (8448 waves x 40 KB, zero reuse) -> L2 queueing bound at ~42 us.
//    256x256 LDS-staged tiles, 528 blocks, 16 waves, wave tile 64x64:
//    L2 traffic 68 MB (5x less), 4x MFMA per staged byte.  Lean epilogue
//    (R6/R7-verified).  WRITE_SIZE is the spill tripwire.
// ---------------------------------------------------------------------------
__global__ __launch_bounds__(1024) void mfma_pass(const unsigned short* __restrict__ u0,
                                                  uint2* __restrict__ list,
                                                  int* __restrict__ gcount) {
  __shared__ __align__(16) unsigned short As[2][16][128][8];  // 64 KB
  __shared__ __align__(16) unsigned short Bs[2][16][128][8];  // 64 KB
  __shared__ uint2 svec[CAPB];                                // 16 KB
  __shared__ int lcnt, lbase;

  const int tid  = threadIdx.x;
  const int lane = tid & 63;
  const int wv   = tid >> 6;          // 0..15
  const int quad = lane >> 4;
  const int l15  = lane & 15;
  const int wm   = wv >> 2;           // 0..3 wave row group (64 rows)
  const int wn   = wv & 3;            // 0..3 wave col group (64 cols)

  // triangular decode over 32 tiles of 256: (ti=ri, tj=cj), cj >= ri
  int rem = blockIdx.x, cj = 0;
  while (rem >= cj + 1) { rem -= cj + 1; ++cj; }
  const int ri = rem;
  const int I0 = ri * 256, J0 = cj * 256;

  if (tid == 0) lcnt = 0;

  // ---- single-shot staging: one 64 KB slab-pair per operand ----
  // 4096 uint4 per array / 1024 threads = EXACTLY 4 iterations (R9 bug: 8).
  const uint4* __restrict__ Asrc = (const uint4*)(u0 + (size_t)ri * 32768);
  const uint4* __restrict__ Bsrc = (const uint4*)(u0 + (size_t)cj * 32768);
  uint4* Ad = (uint4*)As;
  uint4* Bd = (uint4*)Bs;
  {
    uint4 pA[4], pB[4];
#pragma unroll
    for (int it = 0; it < 4; ++it) {
      pA[it] = Asrc[it * 1024 + tid];
      pB[it] = Bsrc[it * 1024 + tid];
    }
#pragma unroll
    for (int it = 0; it < 4; ++it) {
      Ad[it * 1024 + tid] = pA[it];
      Bd[it * 1024 + tid] = pB[it];
    }
  }
  __syncthreads();   // the ONLY barrier before the epilogue

  f32x4 acc[4][4];
#pragma unroll
  for (int mt = 0; mt < 4; ++mt)
#pragma unroll
    for (int nt = 0; nt < 4; ++nt)
#pragma unroll
      for (int g = 0; g < 4; ++g) acc[mt][nt][g] = 0.f;

  const int aslab = wm >> 1, arow0 = (wm & 1) * 64;
  const int bslab = wn >> 1, brow0 = (wn & 1) * 64;

  // ---- K loop: 4 kc x (4 A + 4 B ds_read_b128, 16 MFMAs), no barriers ----
#pragma unroll
  for (int kc = 0; kc < 4; ++kc) {
    const int cq = kc * 4 + quad;
    bf16x8 af[4], bf[4];
#pragma unroll
    for (int mt = 0; mt < 4; ++mt)
      af[mt] = *(const bf16x8*)&As[aslab][cq][arow0 + mt * 16 + l15][0];
#pragma unroll
    for (int nt = 0; nt < 4; ++nt)
      bf[nt] = *(const bf16x8*)&Bs[bslab][cq][brow0 + nt * 16 + l15][0];
#pragma unroll
    for (int mt = 0; mt < 4; ++mt)
#pragma unroll
      for (int nt = 0; nt < 4; ++nt)
        acc[mt][nt] = __builtin_amdgcn_mfma_f32_16x16x32_bf16(
            af[mt], bf[nt], acc[mt][nt], 0, 0, 0);
  }

  // ---- LEAN epilogue: j > i only; emit pair + mirror (one LDS atomic) ----
#pragma unroll
  for (int mt = 0; mt < 4; ++mt)
#pragma unroll
    for (int nt = 0; nt < 4; ++nt)
#pragma unroll
      for (int g = 0; g < 4; ++g) {
        float v = acc[mt][nt][g];
        if (v > COS_THR - EPS_SEL) {
          int i = I0 + wm * 64 + mt * 16 + quad * 4 + g;
          int j = J0 + wn * 64 + nt * 16 + l15;
          if (j > i) {
            int idx = atomicAdd(&lcnt, 2);
            if (idx + 1 < CAPB) {
              svec[idx]     = make_uint2(((unsigned)i << 13) | j,
                                         __float_as_uint(v));
              svec[idx + 1] = make_uint2(((unsigned)j << 13) | i,
                                         __float_as_uint(v));
            }
          }
        }
      }

  __syncthreads();
  int n = min(lcnt, CAPB);
  if (tid == 0) lbase = atomicAdd(gcount, n);
  __syncthreads();
  int base = lbase;
  for (int t = tid; t < n; t += 1024) {
    int o = base + t;
    if (o < LISTCAP) list[o] = svec[t];
  }
}

// ---------------------------------------------------------------------------
// 3) resolve + histogram (own dispatch; borderline exact-dots only ~few K)
// ---------------------------------------------------------------------------
__global__ __launch_bounds__(256) void resolve_hist_k(const float* __restrict__ un,
                                                      const unsigned* __restrict__ excl,
                                                      uint2* __restrict__ list,
                                                      const int* __restrict__ gcount,
                                                      int* __restrict__ row_cnt) {
  int t = blockIdx.x * 256 + threadIdx.x;
  int n = min(*gcount, LISTCAP);
  if (t >= n) return;
  uint2 e = list[t];
  int i = e.x >> 13, j = e.x & 8191;
  unsigned word = excl[(size_t)i * 256 + (j >> 5)];
  bool alive = !((word >> (j & 31)) & 1u);
  float v = __uint_as_float(e.y);
  if (alive && v <= COS_THR + EPS_SEL) {   // borderline: decide exactly
    const float* a = un + (size_t)i * DIMS;
    const float* b = un + (size_t)j * DIMS;
    float s = 0.f;
    for (int k = 0; k < DIMS; ++k) s = fmaf(a[k], b[k], s);
    alive = (s > COS_THR);
    if (alive) list[t] = make_uint2(e.x, __float_as_uint(s));
  }
  if (!alive) list[t] = make_uint2(DEADKEY, 0u);
  else        atomicAdd(&row_cnt[i], 1);
}

// 4) exclusive scan over 8192 row counts (single block)
__global__ __launch_bounds__(256) void scan8k(const int* __restrict__ cnt,
                                              int* __restrict__ off) {
  __shared__ int sm[256];
  int t = threadIdx.x;
  int base = t * 32;
  int s = 0;
  for (int i = 0; i < 32; ++i) s += cnt[base + i];
  sm[t] = s;
  __syncthreads();
  int x = s;
  for (int d = 1; d < 256; d <<= 1) {
    int y = (t >= d) ? sm[t - d] : 0;
    __syncthreads();
    x += y;
    sm[t] = x;
    __syncthreads();
  }
  int run = x - s;
  for (int i = 0; i < 32; ++i) { off[base + i] = run; run += cnt[base + i]; }
  if (t == 255) off[N_USERS] = x;
}

// 5) scatter (skips DEADKEY; pads derived in finalize from M)
__global__ __launch_bounds__(256) void scatter_k(const uint2* __restrict__ list,
                                                 const int* __restrict__ gcount,
                                                 const int* __restrict__ row_off,
                                                 int* __restrict__ row_pos,
                                                 int* __restrict__ cand_i,
                                                 int* __restrict__ cand_j,
                                                 float* __restrict__ cand_v) {
  int t = blockIdx.x * 256 + threadIdx.x;
  int n = min(*gcount, LISTCAP);
  if (t >= n) return;
  uint2 e = list[t];
  if (e.x == DEADKEY) return;
  int i = e.x >> 13, j = e.x & 8191;
  int pos = row_off[i] + atomicAdd(&row_pos[i], 1);
  if (pos < KCAND) {
    cand_i[pos] = i;
    cand_j[pos] = j;
    cand_v[pos] = __uint_as_float(e.y);
  }
}

// 6) sort each row's span ascending by j
__global__ __launch_bounds__(256) void sortrow_k(const int* __restrict__ row_off,
                                                 const int* __restrict__ row_cnt,
                                                 int* __restrict__ cand_j,
                                                 float* __restrict__ cand_v) {
  int r = blockIdx.x * 256 + threadIdx.x;
  if (r >= N_USERS) return;
  int o = row_off[r], c = row_cnt[r];
  if (o + c > KCAND) c = max(0, KCAND - o);
  for (int a = 1; a < c; ++a) {
    int jv = cand_j[o + a];
    float vv = cand_v[o + a];
    int b = a - 1;
    while (b >= 0 && cand_j[o + b] > jv) {
      cand_j[o + b + 1] = cand_j[o + b];
      cand_v[o + b + 1] = cand_v[o + b];
      --b;
    }
    cand_j[o + b + 1] = jv;
    cand_v[o + b + 1] = vv;
  }
}

// 7) finalize (split logits + exact-chain fallback near ties; pads q>=M
//    emit (0,0,w=0) directly — R1/R2-verified)
__global__ __launch_bounds__(256) void finalize_k(const float* __restrict__ ue,
                                                  const float* __restrict__ W,
                                                  const float* __restrict__ b,
                                                  const float* __restrict__ g,
                                                  const int* __restrict__ nz,
                                                  const int* __restrict__ cand_i,
                                                  const int* __restrict__ cand_j,
                                                  const float* __restrict__ cand_v,
                                                  const int* __restrict__ row_off,
                                                  const float4* __restrict__ P,
                                                  float* __restrict__ out) {
  int p = blockIdx.x * 256 + threadIdx.x;
  if (p >= NTOT) return;

  int i, j;
  float wgt;
  if (p < EDGES) {
    i = nz[2 * p];
    j = nz[2 * p + 1];
    wgt = 1.0f;
  } else {
    int q = p - EDGES;
    if (q >= row_off[N_USERS]) {
      // reference pad: pair (0,0), weight max(cos[0,0]=-1, 0) = 0
      out[p] = 0.0f;
      out[NTOT + p] = 0.0f;
      out[2 * NTOT + p] = 0.0f;
      out[3 * NTOT + 2 * p + 0] = 0.0f;
      out[3 * NTOT + 2 * p + 1] = 0.0f;
      return;
    }
    i = cand_i[q];
    j = cand_j[q];
    wgt = fmaxf(cand_v[q], 0.0f);
  }

  float4 Pi = P[i], Pj = P[j];
  float l0 = Pi.x + Pj.y + b[0];
  float l1 = Pi.z + Pj.w + b[1];
  float g0 = g[2 * p], g1 = g[2 * p + 1];
  float s0 = l0 + g0, s1 = l1 + g1;

  if (fabsf(s0 - s1) < LOGIT_MARGIN) {
    const float* ri = ue + (size_t)i * DIMS;
    const float* rj = ue + (size_t)j * DIMS;
    float e0 = 0.f, e1 = 0.f;
    for (int k = 0; k < DIMS; ++k) {
      e0 = fmaf(ri[k], W[k], e0);
      e1 = fmaf(ri[k], W[256 + k], e1);
    }
    for (int k = 0; k < DIMS; ++k) {
      e0 = fmaf(rj[k], W[128 + k], e0);
      e1 = fmaf(rj[k], W[384 + k], e1);
    }
    s0 = (e0 + b[0]) + g0;
    s1 = (e1 + b[1]) + g1;
  }

  float w = (s0 >= s1) ? wgt : 0.0f;

  out[p] = w;
  out[NTOT + p] = w;
  out[2 * NTOT + p] = w;
  out[3 * NTOT + 2 * p + 0] = (float)i;
  out[3 * NTOT + 2 * p + 1] = (float)j;
}

// ---------------------------------------------------------------------------
extern "C" void kernel_launch(void* const* d_in, const int* in_sizes, int n_in,
                              void* d_out, int out_size, void* d_ws, size_t ws_size,
                              hipStream_t stream) {
  (void)in_sizes; (void)n_in; (void)out_size; (void)ws_size;

  const float* user_emb = (const float*)d_in[0];
  const float* W        = (const float*)d_in[1];
  const float* b        = (const float*)d_in[2];
  const float* gnoise   = (const float*)d_in[3];
  const int*   nz       = (const int*)d_in[4];
  float* out = (float*)d_out;

  char* ws = (char*)d_ws;
  float*          un      = (float*)(ws + 0);                        // 4 MB
  unsigned short* u0      = (unsigned short*)(ws + (4u << 20));      // 2 MB (tiled)
  unsigned*       excl    = (unsigned*)(ws + (6u << 20));            // 8 MB
  // zeroed region directly after excl: gcount | row_cnt | row_pos
  char*           zbase   = ws + (14u << 20);
  int*            gcount  = (int*)(zbase);                           // 64 B slot
  int*            row_cnt = (int*)(zbase + 64);                      // 32 KB
  int*            row_pos = (int*)(zbase + 64 + 32768);              // 32 KB
  int*            row_off = (int*)(ws + (14u << 20) + (96u << 10));  // 32.8 KB
  uint2*          list    = (uint2*)(ws + (15u << 20));              // 1 MB
  int*            cand_i  = (int*)(ws + (16u << 20));                // 512 KB
  int*            cand_j  = (int*)(ws + (16u << 20) + (512u << 10)); // 512 KB
  float*          cand_v  = (float*)(ws + (17u << 20));              // 512 KB
  float4*         P       = (float4*)(ws + (17u << 20) + (512u << 10)); // 128 KB

  // one memset: excl (8 MB) + counter region (96 KB) are contiguous
  hipMemsetAsync(excl, 0, (8u << 20) + (96u << 10), stream);

  prep_k<<<256 + EDGES / 256, 256, 0, stream>>>(user_emb, W, nz, un, u0, P, excl);
  mfma_pass<<<NTILES, 1024, 0, stream>>>(u0, list, gcount);
  resolve_hist_k<<<LISTCAP / 256, 256, 0, stream>>>(un, excl, list, gcount,
                                                    row_cnt);
  scan8k<<<1, 256, 0, stream>>>(row_cnt, row_off);
  scatter_k<<<LISTCAP / 256, 256, 0, stream>>>(list, gcount, row_off, row_pos,
                                               cand_i, cand_j, cand_v);
  sortrow_k<<<N_USERS / 256, 256, 0, stream>>>(row_off, row_cnt, cand_j, cand_v);
  finalize_k<<<NTOT / 256, 256, 0, stream>>>(user_emb, W, b, gnoise, nz,
                                             cand_i, cand_j, cand_v, row_off,
                                             P, out);
}